// Round 3
// baseline (108.208 us; speedup 1.0000x reference)
//
#include <hip/hip_runtime.h>

// CenterLoss: loss = mean_b( ||feat[b] - centers[label[b]]|| / count[label[b]] )
// feat: [16384, 512] f32, label: [16384] i32, centers: [10000, 512] f32 -> scalar f32
//
// 2 dispatches:
//  K1: bin-ownership histogram (no global pre-zero) + zeroes d_out
//  K2: one wave per sample, nontemporal float4 feat loads (no reuse -> keep L2
//      for the centers gather), 2-sample ILP unroll, block-reduced atomic.

constexpr int NUM_CLASSES = 10000;
constexpr int FEATURE_DIM = 512;
constexpr int BATCH       = 16384;
constexpr int SAMPLES_PER_BLOCK = 16;   // 4 waves x 4 samples each -> 1024 blocks

constexpr int HIST_BLOCKS    = 20;
constexpr int BINS_PER_BLOCK = NUM_CLASSES / HIST_BLOCKS;  // 500

typedef float vfloat4 __attribute__((ext_vector_type(4)));

__global__ __launch_bounds__(1024) void center_hist_kernel(const int* __restrict__ label,
                                                           int* __restrict__ count,
                                                           float* __restrict__ out) {
    __shared__ int h[BINS_PER_BLOCK];
    const int lo = blockIdx.x * BINS_PER_BLOCK;

    for (int i = threadIdx.x; i < BINS_PER_BLOCK; i += 1024) h[i] = 0;
    __syncthreads();

    for (int i = threadIdx.x; i < BATCH; i += 1024) {
        int lab = label[i] - lo;
        if ((unsigned)lab < (unsigned)BINS_PER_BLOCK) atomicAdd(&h[lab], 1);
    }
    __syncthreads();

    for (int i = threadIdx.x; i < BINS_PER_BLOCK; i += 1024) count[lo + i] = h[i];

    if (blockIdx.x == 0 && threadIdx.x == 0) out[0] = 0.0f;  // K2 accumulates on top
}

__device__ __forceinline__ float sq8(vfloat4 fa, vfloat4 fb, vfloat4 ca, vfloat4 cb) {
    vfloat4 da = fa - ca, db = fb - cb;
    return da.x*da.x + da.y*da.y + da.z*da.z + da.w*da.w
         + db.x*db.x + db.y*db.y + db.z*db.z + db.w*db.w;
}

__global__ __launch_bounds__(256) void center_dist_kernel(const float* __restrict__ feat,
                                                          const int* __restrict__ label,
                                                          const float* __restrict__ centers,
                                                          const int* __restrict__ count,
                                                          float* __restrict__ out) {
    __shared__ float wave_part[4];
    const int wave = threadIdx.x >> 6;   // 0..3
    const int lane = threadIdx.x & 63;   // 0..63

    float local = 0.0f;  // meaningful on lane 0 of each wave
    const int base = blockIdx.x * SAMPLES_PER_BLOCK;

    // Each wave handles 4 samples, processed as 2 ILP pairs.
    #pragma unroll
    for (int p = 0; p < 2; ++p) {
        const int b0 = base + wave + 8 * p;
        const int b1 = b0 + 4;
        const int lab0 = label[b0];   // wave-uniform -> scalar
        const int lab1 = label[b1];

        const vfloat4* f0 = reinterpret_cast<const vfloat4*>(feat    + (size_t)b0   * FEATURE_DIM);
        const vfloat4* f1 = reinterpret_cast<const vfloat4*>(feat    + (size_t)b1   * FEATURE_DIM);
        const vfloat4* c0 = reinterpret_cast<const vfloat4*>(centers + (size_t)lab0 * FEATURE_DIM);
        const vfloat4* c1 = reinterpret_cast<const vfloat4*>(centers + (size_t)lab1 * FEATURE_DIM);

        // 8 independent 16B loads in flight per wave (feat nontemporal: no reuse).
        vfloat4 fa0 = __builtin_nontemporal_load(&f0[lane]);
        vfloat4 fb0 = __builtin_nontemporal_load(&f0[lane + 64]);
        vfloat4 fa1 = __builtin_nontemporal_load(&f1[lane]);
        vfloat4 fb1 = __builtin_nontemporal_load(&f1[lane + 64]);
        vfloat4 ca0 = c0[lane];
        vfloat4 cb0 = c0[lane + 64];
        vfloat4 ca1 = c1[lane];
        vfloat4 cb1 = c1[lane + 64];

        float s2_0 = sq8(fa0, fb0, ca0, cb0);
        float s2_1 = sq8(fa1, fb1, ca1, cb1);

        // Two interleaved 64-lane butterfly reductions (independent chains).
        #pragma unroll
        for (int off = 32; off > 0; off >>= 1) {
            s2_0 += __shfl_down(s2_0, off, 64);
            s2_1 += __shfl_down(s2_1, off, 64);
        }

        if (lane == 0) {
            local += sqrtf(s2_0) / (float)count[lab0]
                   + sqrtf(s2_1) / (float)count[lab1];
        }
    }

    if (lane == 0) wave_part[wave] = local;
    __syncthreads();

    if (threadIdx.x == 0) {
        float sum = wave_part[0] + wave_part[1] + wave_part[2] + wave_part[3];
        atomicAdd(out, sum * (1.0f / (float)BATCH));  // 1024 atomics total
    }
}

extern "C" void kernel_launch(void* const* d_in, const int* in_sizes, int n_in,
                              void* d_out, int out_size, void* d_ws, size_t ws_size,
                              hipStream_t stream) {
    const float* feat    = (const float*)d_in[0];
    const int*   label   = (const int*)  d_in[1];
    const float* centers = (const float*)d_in[2];
    float*       out     = (float*)d_out;
    int*         count   = (int*)d_ws;

    center_hist_kernel<<<HIST_BLOCKS, 1024, 0, stream>>>(label, count, out);

    center_dist_kernel<<<BATCH / SAMPLES_PER_BLOCK, 256, 0, stream>>>(
        feat, label, centers, count, out);
}

// Round 4
// 98.465 us; speedup vs baseline: 1.0990x; 1.0990x over previous
//
#include <hip/hip_runtime.h>

// CenterLoss: loss = mean_b( ||feat[b] - centers[label[b]]|| / count[label[b]] )
// feat: [16384, 512] f32, label: [16384] i32, centers: [10000, 512] f32 -> scalar f32
//
// 2 dispatches:
//  K1: bin-ownership histogram (no global pre-zero) + zeroes d_out
//  K2: one wave per sample-pair (ILP-2), float4-coalesced regular loads
//      (inputs are LLC-resident after harness restore — do NOT bypass cache),
//      32 samples/block -> 512 blocks -> 512 same-address atomics.

constexpr int NUM_CLASSES = 10000;
constexpr int FEATURE_DIM = 512;
constexpr int BATCH       = 16384;
constexpr int SAMPLES_PER_BLOCK = 32;   // 4 waves x 8 samples -> 512 blocks

constexpr int HIST_BLOCKS    = 20;
constexpr int BINS_PER_BLOCK = NUM_CLASSES / HIST_BLOCKS;  // 500

typedef float vfloat4 __attribute__((ext_vector_type(4)));

__global__ __launch_bounds__(1024) void center_hist_kernel(const int* __restrict__ label,
                                                           int* __restrict__ count,
                                                           float* __restrict__ out) {
    __shared__ int h[BINS_PER_BLOCK];
    const int lo = blockIdx.x * BINS_PER_BLOCK;

    for (int i = threadIdx.x; i < BINS_PER_BLOCK; i += 1024) h[i] = 0;
    __syncthreads();

    for (int i = threadIdx.x; i < BATCH; i += 1024) {
        int lab = label[i] - lo;
        if ((unsigned)lab < (unsigned)BINS_PER_BLOCK) atomicAdd(&h[lab], 1);
    }
    __syncthreads();

    for (int i = threadIdx.x; i < BINS_PER_BLOCK; i += 1024) count[lo + i] = h[i];

    if (blockIdx.x == 0 && threadIdx.x == 0) out[0] = 0.0f;  // K2 accumulates on top
}

__device__ __forceinline__ float sq8(vfloat4 fa, vfloat4 fb, vfloat4 ca, vfloat4 cb) {
    vfloat4 da = fa - ca, db = fb - cb;
    return da.x*da.x + da.y*da.y + da.z*da.z + da.w*da.w
         + db.x*db.x + db.y*db.y + db.z*db.z + db.w*db.w;
}

__global__ __launch_bounds__(256) void center_dist_kernel(const float* __restrict__ feat,
                                                          const int* __restrict__ label,
                                                          const float* __restrict__ centers,
                                                          const int* __restrict__ count,
                                                          float* __restrict__ out) {
    __shared__ float wave_part[4];
    const int wave = threadIdx.x >> 6;   // 0..3
    const int lane = threadIdx.x & 63;   // 0..63

    float local = 0.0f;  // meaningful on lane 0 of each wave
    const int base = blockIdx.x * SAMPLES_PER_BLOCK + wave * 8;

    // Each wave handles 8 consecutive samples as 4 ILP pairs.
    #pragma unroll
    for (int p = 0; p < 4; ++p) {
        const int b0 = base + 2 * p;
        const int b1 = b0 + 1;
        const int lab0 = label[b0];   // wave-uniform -> scalar load
        const int lab1 = label[b1];

        const vfloat4* f0 = reinterpret_cast<const vfloat4*>(feat    + (size_t)b0   * FEATURE_DIM);
        const vfloat4* f1 = reinterpret_cast<const vfloat4*>(feat    + (size_t)b1   * FEATURE_DIM);
        const vfloat4* c0 = reinterpret_cast<const vfloat4*>(centers + (size_t)lab0 * FEATURE_DIM);
        const vfloat4* c1 = reinterpret_cast<const vfloat4*>(centers + (size_t)lab1 * FEATURE_DIM);

        // 8 independent 16B-per-lane coalesced loads in flight per wave.
        vfloat4 fa0 = f0[lane];
        vfloat4 fb0 = f0[lane + 64];
        vfloat4 fa1 = f1[lane];
        vfloat4 fb1 = f1[lane + 64];
        vfloat4 ca0 = c0[lane];
        vfloat4 cb0 = c0[lane + 64];
        vfloat4 ca1 = c1[lane];
        vfloat4 cb1 = c1[lane + 64];

        float s2_0 = sq8(fa0, fb0, ca0, cb0);
        float s2_1 = sq8(fa1, fb1, ca1, cb1);

        // Two interleaved 64-lane butterfly reductions (independent chains).
        #pragma unroll
        for (int off = 32; off > 0; off >>= 1) {
            s2_0 += __shfl_down(s2_0, off, 64);
            s2_1 += __shfl_down(s2_1, off, 64);
        }

        if (lane == 0) {
            local += sqrtf(s2_0) / (float)count[lab0]
                   + sqrtf(s2_1) / (float)count[lab1];
        }
    }

    if (lane == 0) wave_part[wave] = local;
    __syncthreads();

    if (threadIdx.x == 0) {
        float sum = wave_part[0] + wave_part[1] + wave_part[2] + wave_part[3];
        atomicAdd(out, sum * (1.0f / (float)BATCH));  // 512 atomics total
    }
}

extern "C" void kernel_launch(void* const* d_in, const int* in_sizes, int n_in,
                              void* d_out, int out_size, void* d_ws, size_t ws_size,
                              hipStream_t stream) {
    const float* feat    = (const float*)d_in[0];
    const int*   label   = (const int*)  d_in[1];
    const float* centers = (const float*)d_in[2];
    float*       out     = (float*)d_out;
    int*         count   = (int*)d_ws;

    center_hist_kernel<<<HIST_BLOCKS, 1024, 0, stream>>>(label, count, out);

    center_dist_kernel<<<BATCH / SAMPLES_PER_BLOCK, 256, 0, stream>>>(
        feat, label, centers, count, out);
}